// Round 3
// baseline (3724.569 us; speedup 1.0000x reference)
//
#include <hip/hip_runtime.h>
#include <math.h>

// Problem constants
#define kB 64
#define kC 1024
#define kT 128
#define kLayers 8
#define kPos 33
#define kEv 16
#define kPar 57
#define kOB (kC / BM)   // o-blocks per layer = 8

// GEMM tile constants
#define BM 128
#define BK 16
#define NTHR 256

// ---------------------------------------------------------------------------
// Positional-encoding projection: posproj[o][t] = b_pos[o] + sum_p w_pos[o][p]*feat[p][t]
// feat = [ramp, sin(2^i ramp), cos(2^i ramp) for i in 0..15]
// ---------------------------------------------------------------------------
__global__ void pos_kernel(const float* __restrict__ w_pos,
                           const float* __restrict__ b_pos,
                           float* __restrict__ posproj) {
    int o = blockIdx.x;        // 1024 blocks
    int t = threadIdx.x;       // 128 threads
    float ramp = -1.0f + 2.0f * (float)t / (float)(kT - 1);
    const float* wr = w_pos + (size_t)o * kPos;
    float s = b_pos[o] + wr[0] * ramp;
    float p2 = 1.0f;
#pragma unroll
    for (int i = 0; i < 16; ++i) {
        float sv, cv;
        sincosf(p2 * ramp, &sv, &cv);  // fp32 product then sin/cos, same as ref
        s += wr[1 + 2 * i] * sv + wr[2 + 2 * i] * cv;
        p2 *= 2.0f;
    }
    posproj[(size_t)o * kT + t] = s;
}

// ---------------------------------------------------------------------------
// Algebraic collapse of the tail: out = val*(w_par@(w_vec@g + b_vec)) + b_par
//   Mt[k][p]  = (w_par @ w_vec)[p][k]   (transposed store: coalesced final reads)
//   pbias[p]  = (w_par @ b_vec)[p]
// Removes the need to materialize vecs[B,C,T] (2.1 GFLOP/event -> 0.12).
// ---------------------------------------------------------------------------
__global__ void mt_kernel(const float* __restrict__ w_par,
                          const float* __restrict__ w_vec,
                          const float* __restrict__ b_vec,
                          float* __restrict__ Mt,
                          float* __restrict__ pbias) {
    if (blockIdx.x == kPar) {
        int p = threadIdx.x;
        if (p < kPar) {
            float s = 0.f;
            for (int c = 0; c < kC; ++c) s += w_par[(size_t)p * kC + c] * b_vec[c];
            pbias[p] = s;
        }
        return;
    }
    int p = blockIdx.x;          // 0..56
    int k = threadIdx.x * 4;     // 256 threads * 4 = 1024
    float mx = 0.f, my = 0.f, mz = 0.f, mw = 0.f;
    for (int o = 0; o < kC; ++o) {
        float wp = w_par[(size_t)p * kC + o];
        float4 wv = *(const float4*)(w_vec + (size_t)o * kC + k);
        mx += wp * wv.x; my += wp * wv.y; mz += wp * wv.z; mw += wp * wv.w;
    }
    Mt[(size_t)(k + 0) * kPar + p] = mx;
    Mt[(size_t)(k + 1) * kPar + p] = my;
    Mt[(size_t)(k + 2) * kPar + p] = mz;
    Mt[(size_t)(k + 3) * kPar + p] = mw;
}

// ---------------------------------------------------------------------------
// Spec GEMM: h[b][o][t] = sum_c w_spec[o][c]*x[b][c][t] + b_spec[o] + posproj[o][t]
// Block: o-tile of 128 x full T=128 for one batch b. 256 threads, 8x8 micro-tile.
// A-reads broadcast within quarter-wave (conflict-free); B-reads 2-way (free, m136).
// ---------------------------------------------------------------------------
__global__ __launch_bounds__(NTHR) void spec_gemm(
    const float* __restrict__ x, const float* __restrict__ w_spec,
    const float* __restrict__ b_spec, const float* __restrict__ posproj,
    float* __restrict__ h) {
    __shared__ float As[BK][BM];
    __shared__ float Bs[BK][kT];
    const int obase = blockIdx.x * BM;
    const int b = blockIdx.y;
    const int tid = threadIdx.x;
    const int tx4 = (tid & 15) * 4;
    const int ty4 = (tid >> 4) * 4;
    const float* xb = x + (size_t)b * kC * kT;
    float acc[8][8] = {};

    for (int kc = 0; kc < kC; kc += BK) {
        __syncthreads();
        {   // stage weights: As[c'][o] = w_spec[obase+o][kc+c']
            int oo = tid >> 1;
            int ccb = (tid & 1) * 8;
            const float* wrow = w_spec + (size_t)(obase + oo) * kC + kc + ccb;
            float4 v0 = *(const float4*)(wrow);
            float4 v1 = *(const float4*)(wrow + 4);
            As[ccb + 0][oo] = v0.x; As[ccb + 1][oo] = v0.y;
            As[ccb + 2][oo] = v0.z; As[ccb + 3][oo] = v0.w;
            As[ccb + 4][oo] = v1.x; As[ccb + 5][oo] = v1.y;
            As[ccb + 6][oo] = v1.z; As[ccb + 7][oo] = v1.w;
        }
#pragma unroll
        for (int pass = 0; pass < 2; ++pass) {   // stage x rows
            int row = (tid >> 5) + pass * 8;
            int col = (tid & 31) * 4;
            *(float4*)&Bs[row][col] = *(const float4*)(xb + (size_t)(kc + row) * kT + col);
        }
        __syncthreads();
#pragma unroll
        for (int kk = 0; kk < BK; ++kk) {
            float a[8], bb[8];
            *(float4*)&a[0] = *(float4*)&As[kk][ty4];
            *(float4*)&a[4] = *(float4*)&As[kk][64 + ty4];
            *(float4*)&bb[0] = *(float4*)&Bs[kk][tx4];
            *(float4*)&bb[4] = *(float4*)&Bs[kk][64 + tx4];
#pragma unroll
            for (int m = 0; m < 8; ++m)
#pragma unroll
                for (int n = 0; n < 8; ++n) acc[m][n] += a[m] * bb[n];
        }
    }
#pragma unroll
    for (int m = 0; m < 8; ++m) {
        int o = obase + (m < 4 ? ty4 + m : 64 + ty4 + m - 4);
        float bias = b_spec[o];
        const float* pp = posproj + (size_t)o * kT;
        float* hrow = h + ((size_t)b * kC + o) * kT;
#pragma unroll
        for (int half = 0; half < 2; ++half) {
            int t0 = half * 64 + tx4;
            float4 pv = *(const float4*)(pp + t0);
            float4 r;
            r.x = acc[m][half * 4 + 0] + bias + pv.x;
            r.y = acc[m][half * 4 + 1] + bias + pv.y;
            r.z = acc[m][half * 4 + 2] + bias + pv.z;
            r.w = acc[m][half * 4 + 3] + bias + pv.w;
            *(float4*)(hrow + t0) = r;
        }
    }
}

// ---------------------------------------------------------------------------
// Conv layer GEMM (anti-causal dilated conv, K=2) + leaky_relu + residual.
// conv[o][t] = sum_c W0[o][c]*h[c][t] + W1[o][c]*h[c][t+d]   (t+d>=T -> 0)
// Shifted tap read from the SAME LDS tile: rows padded to 192, tail zeroed once
// (tail is only ever READ after the first barrier; stage writes cols 0..127 only).
// Writes un-normalized h_next + DETERMINISTIC per-(o-block,b,t) sumsq partials.
// ---------------------------------------------------------------------------
template <int DIL>
__global__ __launch_bounds__(NTHR) void conv_gemm(
    const float* __restrict__ hin, const float* __restrict__ w,
    const float* __restrict__ bconv, float* __restrict__ hout,
    float* __restrict__ ssp /* [kOB][kB][kT] */) {
    __shared__ float As0[BK][BM];
    __shared__ float As1[BK][BM];
    __shared__ float Bs[BK][192];
    __shared__ float red[16][kT];
    const int obase = blockIdx.x * BM;
    const int b = blockIdx.y;
    const int tid = threadIdx.x;
    const int tx4 = (tid & 15) * 4;
    const int ty4 = (tid >> 4) * 4;
    const float* hb = hin + (size_t)b * kC * kT;
    float acc[8][8] = {};

    {   // zero tail region [128..192) once; guarded by the loop's first barrier
        int row = tid >> 4;
        int col = 128 + (tid & 15) * 4;
        *(float4*)&Bs[row][col] = make_float4(0.f, 0.f, 0.f, 0.f);
    }

    for (int kc = 0; kc < kC; kc += BK) {
        __syncthreads();
        {   // stage W0/W1: layout enc_w[o][c][k], k fastest -> float4 = 2 c's x 2 taps
            int oo = tid >> 1;
            int ccb = (tid & 1) * 8;
            const float* wrow = w + ((size_t)(obase + oo) * kC + kc + ccb) * 2;
#pragma unroll
            for (int q = 0; q < 4; ++q) {
                float4 v = *(const float4*)(wrow + q * 4);
                As0[ccb + 2 * q + 0][oo] = v.x; As1[ccb + 2 * q + 0][oo] = v.y;
                As0[ccb + 2 * q + 1][oo] = v.z; As1[ccb + 2 * q + 1][oo] = v.w;
            }
        }
#pragma unroll
        for (int pass = 0; pass < 2; ++pass) {   // stage h rows (valid region only)
            int row = (tid >> 5) + pass * 8;
            int col = (tid & 31) * 4;
            *(float4*)&Bs[row][col] = *(const float4*)(hb + (size_t)(kc + row) * kT + col);
        }
        __syncthreads();
#pragma unroll
        for (int kk = 0; kk < BK; ++kk) {
            float a0[8], a1[8], bv[8], bs[8];
            *(float4*)&a0[0] = *(float4*)&As0[kk][ty4];
            *(float4*)&a0[4] = *(float4*)&As0[kk][64 + ty4];
            *(float4*)&a1[0] = *(float4*)&As1[kk][ty4];
            *(float4*)&a1[4] = *(float4*)&As1[kk][64 + ty4];
            *(float4*)&bv[0] = *(float4*)&Bs[kk][tx4];
            *(float4*)&bv[4] = *(float4*)&Bs[kk][64 + tx4];
            if constexpr ((DIL & 3) == 0) {
                *(float4*)&bs[0] = *(float4*)&Bs[kk][tx4 + DIL];
                *(float4*)&bs[4] = *(float4*)&Bs[kk][64 + tx4 + DIL];
            } else {
#pragma unroll
                for (int n = 0; n < 4; ++n) bs[n] = Bs[kk][tx4 + DIL + n];
#pragma unroll
                for (int n = 0; n < 4; ++n) bs[4 + n] = Bs[kk][64 + tx4 + DIL + n];
            }
#pragma unroll
            for (int m = 0; m < 8; ++m)
#pragma unroll
                for (int n = 0; n < 8; ++n) {
                    acc[m][n] += a0[m] * bv[n];
                    acc[m][n] += a1[m] * bs[n];
                }
        }
    }

    // epilogue: bias + leaky_relu + residual, write h_pre, per-t sumsq partials
    float tsum[8] = {};
#pragma unroll
    for (int m = 0; m < 8; ++m) {
        int o = obase + (m < 4 ? ty4 + m : 64 + ty4 + m - 4);
        float bias = bconv[o];
        const float* srow = hb + (size_t)o * kT;
        float* drow = hout + ((size_t)b * kC + o) * kT;
#pragma unroll
        for (int half = 0; half < 2; ++half) {
            int t0 = half * 64 + tx4;
            float4 sk = *(const float4*)(srow + t0);
            float v[4];
            v[0] = acc[m][half * 4 + 0] + bias;
            v[1] = acc[m][half * 4 + 1] + bias;
            v[2] = acc[m][half * 4 + 2] + bias;
            v[3] = acc[m][half * 4 + 3] + bias;
            float s[4] = {sk.x, sk.y, sk.z, sk.w};
            float4 r;
            float* rp = &r.x;
#pragma unroll
            for (int j = 0; j < 4; ++j) {
                float lv = v[j] >= 0.f ? v[j] : 0.2f * v[j];
                float hp = lv + s[j];
                rp[j] = hp;
                tsum[half * 4 + j] += hp * hp;
            }
            *(float4*)(drow + t0) = r;
        }
    }
    int ty = tid >> 4;
#pragma unroll
    for (int n = 0; n < 8; ++n) {
        int t = (n < 4 ? tx4 + n : 64 + tx4 + n - 4);
        red[ty][t] = tsum[n];   // (ty,t) covered exactly once across the block
    }
    __syncthreads();
    if (tid < kT) {
        float s = 0.f;
#pragma unroll
        for (int r = 0; r < 16; ++r) s += red[r][tid];
        // deterministic: one partial slot per o-block, no atomics
        ssp[((size_t)blockIdx.x * kB + b) * kT + tid] = s;
    }
}

// ---------------------------------------------------------------------------
// rnorm[b][t] = 1 / (sqrt(sum over 8 o-block partials) + 1e-8), fixed order.
// ---------------------------------------------------------------------------
__global__ void normfac(const float* __restrict__ ssp, float* __restrict__ rn) {
    int b = blockIdx.x;
    int t = threadIdx.x;
    float s = 0.f;
#pragma unroll
    for (int j = 0; j < kOB; ++j) s += ssp[((size_t)j * kB + b) * kT + t];
    rn[b * kT + t] = 1.0f / (sqrtf(s) + 1e-8f);
}

// ---------------------------------------------------------------------------
// Normalize h in place by rnorm (multiply), accumulate acc.
// ---------------------------------------------------------------------------
__global__ void norm_acc(const float* __restrict__ rnorm, float* __restrict__ h,
                         float* __restrict__ acc, int first) {
    const int n4 = kB * kC * kT / 4;
    for (int i = blockIdx.x * blockDim.x + threadIdx.x; i < n4;
         i += gridDim.x * blockDim.x) {
        size_t e = (size_t)i * 4;
        int b = (int)(e / (kC * kT));
        int t = (int)(e % kT);       // multiple of 4; kT % 4 == 0
        float4 rn = *(const float4*)(rnorm + b * kT + t);
        float4 hv = ((float4*)h)[i];
        float4 r;
        r.x = hv.x * rn.x;
        r.y = hv.y * rn.y;
        r.z = hv.z * rn.z;
        r.w = hv.w * rn.w;
        ((float4*)h)[i] = r;
        if (first) {
            ((float4*)acc)[i] = r;
        } else {
            float4 a = ((float4*)acc)[i];
            a.x += r.x; a.y += r.y; a.z += r.z; a.w += r.w;
            ((float4*)acc)[i] = a;
        }
    }
}

// ---------------------------------------------------------------------------
// switch partials: swp[cblk][b][t] = sum over 128 channels of w_sw[c]*acc[b][c][t]
// (deterministic; summed in fixed order inside topk_kernel)
// ---------------------------------------------------------------------------
__global__ void switch_partial(const float* __restrict__ acc,
                               const float* __restrict__ w_sw,
                               float* __restrict__ swp) {
    int b = blockIdx.x;
    int cblk = blockIdx.y;
    int t = threadIdx.x & 127;
    int half = threadIdx.x >> 7;
    int cbase = cblk * 128 + half * 64;
    const float* arow = acc + ((size_t)b * kC + cbase) * kT + t;
    float p = 0.f;
    for (int j = 0; j < 64; ++j) p += w_sw[cbase + j] * arow[(size_t)j * kT];
    __shared__ float red2[2][128];
    red2[half][t] = p;
    __syncthreads();
    if (half == 0)
        swp[((size_t)cblk * kB + b) * kT + t] = red2[0][t] + red2[1][t];
}

// ---------------------------------------------------------------------------
// Top-16 of |switch+b_sw| per batch. Values desc, ties -> lower index (JAX).
// ---------------------------------------------------------------------------
__global__ void topk_kernel(const float* __restrict__ swp,
                            const float* __restrict__ b_sw,
                            float* __restrict__ vals, int* __restrict__ idxs) {
    int b = blockIdx.x;
    int t = threadIdx.x;  // 128 threads
    __shared__ float cur[128];
    __shared__ float rv[128];
    __shared__ int ri[128];
    {
        float s = b_sw[0];
#pragma unroll
        for (int j = 0; j < kC / 128; ++j)
            s += swp[((size_t)j * kB + b) * kT + t];
        cur[t] = fabsf(s);
    }
    __syncthreads();
    for (int r = 0; r < kEv; ++r) {
        rv[t] = cur[t];
        ri[t] = t;
        __syncthreads();
        for (int s = 64; s >= 1; s >>= 1) {
            if (t < s) {
                float v2 = rv[t + s];
                int i2 = ri[t + s];
                if (v2 > rv[t] || (v2 == rv[t] && i2 < ri[t])) { rv[t] = v2; ri[t] = i2; }
            }
            __syncthreads();
        }
        if (t == 0) {
            vals[b * kEv + r] = rv[0];
            idxs[b * kEv + r] = ri[0];
            cur[ri[0]] = -1.0f;  // values are >=0 (abs), so -1 excludes
        }
        __syncthreads();
    }
}

// ---------------------------------------------------------------------------
// Final: out[b][n][p] = val * (sum_k Mt[k][p]*acc[b][k][idx] + pbias[p]) + b_par[p]
// ---------------------------------------------------------------------------
__global__ void final_kernel(const float* __restrict__ acc,
                             const float* __restrict__ Mt,
                             const float* __restrict__ pbias,
                             const float* __restrict__ b_par,
                             const float* __restrict__ vals,
                             const int* __restrict__ idxs,
                             float* __restrict__ out) {
    int bn = blockIdx.x;
    int b = bn >> 4;
    int tid = threadIdx.x;  // 256
    __shared__ float gs[kC];
    __shared__ float redf[4][64];
    int idx = idxs[bn];
    float val = vals[bn];
#pragma unroll
    for (int j = 0; j < 4; ++j) {
        int k = tid * 4 + j;
        gs[k] = acc[((size_t)b * kC + k) * kT + idx];
    }
    __syncthreads();
    int kg = tid >> 6;
    int pp = tid & 63;
    float partial = 0.f;
    if (pp < kPar) {
        for (int j = 0; j < 256; ++j) {
            int k = kg * 256 + j;
            partial += Mt[(size_t)k * kPar + pp] * gs[k];
        }
    }
    redf[kg][pp] = partial;
    __syncthreads();
    if (kg == 0 && pp < kPar) {
        float s = redf[0][pp] + redf[1][pp] + redf[2][pp] + redf[3][pp];
        out[(size_t)bn * kPar + pp] = val * (s + pbias[pp]) + b_par[pp];
    }
}

// ---------------------------------------------------------------------------
extern "C" void kernel_launch(void* const* d_in, const int* in_sizes, int n_in,
                              void* d_out, int out_size, void* d_ws, size_t ws_size,
                              hipStream_t stream) {
    (void)in_sizes; (void)n_in; (void)out_size; (void)ws_size;
    const float* x      = (const float*)d_in[0];
    const float* w_spec = (const float*)d_in[1];
    const float* b_spec = (const float*)d_in[2];
    const float* w_pos  = (const float*)d_in[3];
    const float* b_pos  = (const float*)d_in[4];
    const float* enc_w  = (const float*)d_in[5];
    const float* enc_b  = (const float*)d_in[6];
    const float* w_vec  = (const float*)d_in[7];
    const float* b_vec  = (const float*)d_in[8];
    const float* w_sw   = (const float*)d_in[9];
    const float* b_sw   = (const float*)d_in[10];
    const float* w_par  = (const float*)d_in[11];
    const float* b_par  = (const float*)d_in[12];
    float* out = (float*)d_out;

    const size_t SLAB = (size_t)kB * kC * kT;   // 8,388,608 floats
    float* h_a     = (float*)d_ws;
    float* h_b     = h_a + SLAB;
    float* acc     = h_b + SLAB;
    float* posproj = acc + SLAB;                         // C*T
    float* ssp     = posproj + (size_t)kC * kT;          // 8*B*T (per-layer reuse)
    float* rnorm   = ssp + (size_t)kOB * kB * kT;        // B*T
    float* swp     = rnorm + (size_t)kB * kT;            // 8*B*T
    float* vals    = swp + (size_t)kOB * kB * kT;        // B*16
    int*   idxs    = (int*)(vals + kB * kEv);            // B*16
    float* Mt      = (float*)(idxs + kB * kEv);          // 1024*57
    float* pbias   = Mt + (size_t)kC * kPar;             // 57 (pad)

    // No memsets needed: every buffer is fully written before first read,
    // every call (harness re-poisons d_ws with 0xAA before each timed launch).

    pos_kernel<<<kC, kT, 0, stream>>>(w_pos, b_pos, posproj);
    mt_kernel<<<kPar + 1, 256, 0, stream>>>(w_par, w_vec, b_vec, Mt, pbias);
    spec_gemm<<<dim3(kC / BM, kB), NTHR, 0, stream>>>(x, w_spec, b_spec, posproj, h_a);

    const int dils[kLayers] = {1, 2, 4, 8, 16, 32, 64, 1};
    float* cur = h_a;
    float* nxt = h_b;
    for (int i = 0; i < kLayers; ++i) {
        const float* wi = enc_w + (size_t)i * kC * kC * 2;
        const float* bi = enc_b + (size_t)i * kC;
        dim3 grid(kC / BM, kB);
        switch (dils[i]) {
            case 1:  conv_gemm<1><<<grid, NTHR, 0, stream>>>(cur, wi, bi, nxt, ssp); break;
            case 2:  conv_gemm<2><<<grid, NTHR, 0, stream>>>(cur, wi, bi, nxt, ssp); break;
            case 4:  conv_gemm<4><<<grid, NTHR, 0, stream>>>(cur, wi, bi, nxt, ssp); break;
            case 8:  conv_gemm<8><<<grid, NTHR, 0, stream>>>(cur, wi, bi, nxt, ssp); break;
            case 16: conv_gemm<16><<<grid, NTHR, 0, stream>>>(cur, wi, bi, nxt, ssp); break;
            case 32: conv_gemm<32><<<grid, NTHR, 0, stream>>>(cur, wi, bi, nxt, ssp); break;
            case 64: conv_gemm<64><<<grid, NTHR, 0, stream>>>(cur, wi, bi, nxt, ssp); break;
        }
        normfac<<<kB, kT, 0, stream>>>(ssp, rnorm);
        norm_acc<<<2048, 256, 0, stream>>>(rnorm, nxt, acc, i == 0 ? 1 : 0);
        float* tmp = cur; cur = nxt; nxt = tmp;
    }

    switch_partial<<<dim3(kB, kC / 128), 256, 0, stream>>>(acc, w_sw, swp);
    topk_kernel<<<kB, 128, 0, stream>>>(swp, b_sw, vals, idxs);
    final_kernel<<<kB * kEv, 256, 0, stream>>>(acc, Mt, pbias, b_par, vals, idxs, out);
}

// Round 4
// 1536.982 us; speedup vs baseline: 2.4233x; 2.4233x over previous
//
#include <hip/hip_runtime.h>
#include <math.h>

// Problem constants
#define kB 64
#define kC 1024
#define kT 128
#define kLayers 8
#define kPos 33
#define kEv 16
#define kPar 57

// GEMM tile constants
#define BM 128
#define kOB (kC / BM)   // o-blocks per layer = 8
#define BK 16
#define NTHR 256

#define SLAB ((size_t)kB * kC * kT)   // 8,388,608 elements

typedef __attribute__((ext_vector_type(8))) short short8v;
typedef __attribute__((ext_vector_type(4))) float float4v;
typedef __attribute__((ext_vector_type(4))) unsigned short ushort4v;

// RNE fp32 -> bf16 (bits) and back; hi/lo split: f = hi + lo + O(2^-18 |f|)
__device__ __forceinline__ unsigned short bf_hi(float f) {
    unsigned int x = __float_as_uint(f);
    unsigned int r = x + 0x7fffu + ((x >> 16) & 1u);
    return (unsigned short)(r >> 16);
}
__device__ __forceinline__ float bf_f(unsigned short u) {
    return __uint_as_float(((unsigned int)u) << 16);
}

// ---------------------------------------------------------------------------
// Positional-encoding projection (unchanged, verified round 3)
// ---------------------------------------------------------------------------
__global__ void pos_kernel(const float* __restrict__ w_pos,
                           const float* __restrict__ b_pos,
                           float* __restrict__ posproj) {
    int o = blockIdx.x;
    int t = threadIdx.x;
    float ramp = -1.0f + 2.0f * (float)t / (float)(kT - 1);
    const float* wr = w_pos + (size_t)o * kPos;
    float s = b_pos[o] + wr[0] * ramp;
    float p2 = 1.0f;
#pragma unroll
    for (int i = 0; i < 16; ++i) {
        float sv, cv;
        sincosf(p2 * ramp, &sv, &cv);
        s += wr[1 + 2 * i] * sv + wr[2 + 2 * i] * cv;
        p2 *= 2.0f;
    }
    posproj[(size_t)o * kT + t] = s;
}

// ---------------------------------------------------------------------------
// Mt = (w_par @ w_vec) transposed, pbias = w_par @ b_vec (unchanged)
// ---------------------------------------------------------------------------
__global__ void mt_kernel(const float* __restrict__ w_par,
                          const float* __restrict__ w_vec,
                          const float* __restrict__ b_vec,
                          float* __restrict__ Mt,
                          float* __restrict__ pbias) {
    if (blockIdx.x == kPar) {
        int p = threadIdx.x;
        if (p < kPar) {
            float s = 0.f;
            for (int c = 0; c < kC; ++c) s += w_par[(size_t)p * kC + c] * b_vec[c];
            pbias[p] = s;
        }
        return;
    }
    int p = blockIdx.x;
    int k = threadIdx.x * 4;
    float mx = 0.f, my = 0.f, mz = 0.f, mw = 0.f;
    for (int o = 0; o < kC; ++o) {
        float wp = w_par[(size_t)p * kC + o];
        float4 wv = *(const float4*)(w_vec + (size_t)o * kC + k);
        mx += wp * wv.x; my += wp * wv.y; mz += wp * wv.z; mw += wp * wv.w;
    }
    Mt[(size_t)(k + 0) * kPar + p] = mx;
    Mt[(size_t)(k + 1) * kPar + p] = my;
    Mt[(size_t)(k + 2) * kPar + p] = mz;
    Mt[(size_t)(k + 3) * kPar + p] = mw;
}

// ---------------------------------------------------------------------------
// Spec GEMM (fp32, unchanged, verified round 3). Writes h0 -> hpre buffer.
// ---------------------------------------------------------------------------
__global__ __launch_bounds__(NTHR) void spec_gemm(
    const float* __restrict__ x, const float* __restrict__ w_spec,
    const float* __restrict__ b_spec, const float* __restrict__ posproj,
    float* __restrict__ h) {
    __shared__ float As[BK][BM];
    __shared__ float Bs[BK][kT];
    const int obase = blockIdx.x * BM;
    const int b = blockIdx.y;
    const int tid = threadIdx.x;
    const int tx4 = (tid & 15) * 4;
    const int ty4 = (tid >> 4) * 4;
    const float* xb = x + (size_t)b * kC * kT;
    float acc[8][8] = {};

    for (int kc = 0; kc < kC; kc += BK) {
        __syncthreads();
        {
            int oo = tid >> 1;
            int ccb = (tid & 1) * 8;
            const float* wrow = w_spec + (size_t)(obase + oo) * kC + kc + ccb;
            float4 v0 = *(const float4*)(wrow);
            float4 v1 = *(const float4*)(wrow + 4);
            As[ccb + 0][oo] = v0.x; As[ccb + 1][oo] = v0.y;
            As[ccb + 2][oo] = v0.z; As[ccb + 3][oo] = v0.w;
            As[ccb + 4][oo] = v1.x; As[ccb + 5][oo] = v1.y;
            As[ccb + 6][oo] = v1.z; As[ccb + 7][oo] = v1.w;
        }
#pragma unroll
        for (int pass = 0; pass < 2; ++pass) {
            int row = (tid >> 5) + pass * 8;
            int col = (tid & 31) * 4;
            *(float4*)&Bs[row][col] = *(const float4*)(xb + (size_t)(kc + row) * kT + col);
        }
        __syncthreads();
#pragma unroll
        for (int kk = 0; kk < BK; ++kk) {
            float a[8], bb[8];
            *(float4*)&a[0] = *(float4*)&As[kk][ty4];
            *(float4*)&a[4] = *(float4*)&As[kk][64 + ty4];
            *(float4*)&bb[0] = *(float4*)&Bs[kk][tx4];
            *(float4*)&bb[4] = *(float4*)&Bs[kk][64 + tx4];
#pragma unroll
            for (int m = 0; m < 8; ++m)
#pragma unroll
                for (int n = 0; n < 8; ++n) acc[m][n] += a[m] * bb[n];
        }
    }
#pragma unroll
    for (int m = 0; m < 8; ++m) {
        int o = obase + (m < 4 ? ty4 + m : 64 + ty4 + m - 4);
        float bias = b_spec[o];
        const float* pp = posproj + (size_t)o * kT;
        float* hrow = h + ((size_t)b * kC + o) * kT;
#pragma unroll
        for (int half = 0; half < 2; ++half) {
            int t0 = half * 64 + tx4;
            float4 pv = *(const float4*)(pp + t0);
            float4 r;
            r.x = acc[m][half * 4 + 0] + bias + pv.x;
            r.y = acc[m][half * 4 + 1] + bias + pv.y;
            r.z = acc[m][half * 4 + 2] + bias + pv.z;
            r.w = acc[m][half * 4 + 3] + bias + pv.w;
            *(float4*)(hrow + t0) = r;
        }
    }
}

// ---------------------------------------------------------------------------
// Weight pre-convert: enc_w layer [o][c][tap] fp32 -> wpl[pl(hi/lo)][tap][o][c] bf16
// ---------------------------------------------------------------------------
__global__ void wconv_kernel(const float* __restrict__ src,
                             unsigned short* __restrict__ wpl) {
    int o = blockIdx.x;
    int tid = threadIdx.x;
    const float* r = src + (size_t)o * (2 * kC) + tid * 8;
    float4 v0 = *(const float4*)r;
    float4 v1 = *(const float4*)(r + 4);
    float t0v[4] = {v0.x, v0.z, v1.x, v1.z};   // tap0, c = c0..c0+3
    float t1v[4] = {v0.y, v0.w, v1.y, v1.w};   // tap1
    int c0 = tid * 4;
    ushort4v h0, l0, h1, l1;
#pragma unroll
    for (int j = 0; j < 4; ++j) {
        unsigned short h = bf_hi(t0v[j]); h0[j] = h; l0[j] = bf_hi(t0v[j] - bf_f(h));
        unsigned short g = bf_hi(t1v[j]); h1[j] = g; l1[j] = bf_hi(t1v[j] - bf_f(g));
    }
    size_t base = (size_t)o * kC + c0;
    const size_t P = (size_t)kC * kC;
    *(ushort4v*)&wpl[base] = h0;            // hi tap0
    *(ushort4v*)&wpl[base + P] = h1;        // hi tap1
    *(ushort4v*)&wpl[base + 2 * P] = l0;    // lo tap0
    *(ushort4v*)&wpl[base + 3 * P] = l1;    // lo tap1
}

// ---------------------------------------------------------------------------
// MFMA conv layer: D[o][t] = sum_c W0[o][c] h[c][t] + W1[o][c] h[c][t+d]
// Split bf16 (hi/lo, 3 products) accumulating fp32; epilogue: bias + leaky +
// residual(from planes) -> hpre, per-(b,t) sumsq partials -> ssp.
// LDS: A [tap][128 o][8x16B chunks hi/lo interleaved, XOR(row&7) swizzle]
//      B [192 t][same], rows 128..191 zeroed once (anti-causal pad).
// ---------------------------------------------------------------------------
template <int DIL>
__global__ __launch_bounds__(NTHR, 2) void conv_mfma(
    const unsigned short* __restrict__ tpl,   // [2][b][t][c] planes (hi, lo)
    const unsigned short* __restrict__ wpl,   // [2][tap][o][c]
    const float* __restrict__ bconv,
    float* __restrict__ hpre,
    float* __restrict__ ssp) {
    __shared__ short Asl[2 * 128 * 64];   // 32 KB
    __shared__ short Bsl[192 * 64];       // 24 KB
    __shared__ float red[1024];           // 4 KB
    const int tid = threadIdx.x;
    const int obase = blockIdx.x * BM;
    const int b = blockIdx.y;
    const int lane = tid & 63;
    const int w = tid >> 6;
    const int r16 = lane & 15;
    const int kq = lane >> 4;
    const int mrow = (w & 1) * 64;
    const int ncol = (w >> 1) * 64;
    const size_t PW = (size_t)kC * kC;    // wpl plane stride (per tap within pl: kC*kC)

    float4v acc[4][4];
#pragma unroll
    for (int m = 0; m < 4; ++m)
#pragma unroll
        for (int n = 0; n < 4; ++n) {
            float4v z = {0.f, 0.f, 0.f, 0.f};
            acc[m][n] = z;
        }

    {   // zero B rows 128..191 once (t >= T -> 0, covers anti-causal pad)
        short8v z = {0, 0, 0, 0, 0, 0, 0, 0};
#pragma unroll
        for (int r = 0; r < 2; ++r) {
            int cw = r * 256 + tid;
            int t = 128 + (cw >> 3);
            int g = cw & 7;
            *(short8v*)&Bsl[t * 64 + ((g ^ (t & 7)) << 3)] = z;
        }
    }

    for (int kc = 0; kc < kC; kc += 32) {
        __syncthreads();
        // stage A: 2 taps x 128 o x 8 chunks (chunk g: plane=g&1, c-sub=(g>>1)*8)
#pragma unroll
        for (int r = 0; r < 8; ++r) {
            int cw = r * 256 + tid;
            int g = cw & 7;
            int o = (cw >> 3) & 127;
            int tap = cw >> 10;
            size_t src = ((size_t)((g & 1) * 2 + tap) * kC + (obase + o)) * kC + kc + ((g >> 1) << 3);
            short8v v = *(const short8v*)&wpl[src];
            *(short8v*)&Asl[tap * 8192 + o * 64 + ((g ^ (o & 7)) << 3)] = v;
        }
        // stage B: 128 t x 8 chunks from hT planes [pl][b][t][c]
#pragma unroll
        for (int r = 0; r < 4; ++r) {
            int cw = r * 256 + tid;
            int g = cw & 7;
            int t = cw >> 3;
            size_t src = (size_t)(g & 1) * SLAB + ((size_t)b * kT + t) * kC + kc + ((g >> 1) << 3);
            short8v v = *(const short8v*)&tpl[src];
            *(short8v*)&Bsl[t * 64 + ((g ^ (t & 7)) << 3)] = v;
        }
        __syncthreads();
#pragma unroll
        for (int tap = 0; tap < 2; ++tap) {
            short8v ah[4], al[4], bh[4], bl[4];
#pragma unroll
            for (int m = 0; m < 4; ++m) {
                int ol = mrow + m * 16 + r16;
                const short* rowp = &Asl[tap * 8192 + ol * 64];
                ah[m] = *(const short8v*)&rowp[(((kq << 1)) ^ (ol & 7)) << 3];
                al[m] = *(const short8v*)&rowp[(((kq << 1) | 1) ^ (ol & 7)) << 3];
            }
#pragma unroll
            for (int n = 0; n < 4; ++n) {
                int tr = ncol + n * 16 + r16 + tap * DIL;
                const short* rowp = &Bsl[tr * 64];
                bh[n] = *(const short8v*)&rowp[(((kq << 1)) ^ (tr & 7)) << 3];
                bl[n] = *(const short8v*)&rowp[(((kq << 1) | 1) ^ (tr & 7)) << 3];
            }
#pragma unroll
            for (int m = 0; m < 4; ++m)
#pragma unroll
                for (int n = 0; n < 4; ++n) {
                    acc[m][n] = __builtin_amdgcn_mfma_f32_16x16x32_bf16(ah[m], bh[n], acc[m][n], 0, 0, 0);
                    acc[m][n] = __builtin_amdgcn_mfma_f32_16x16x32_bf16(ah[m], bl[n], acc[m][n], 0, 0, 0);
                    acc[m][n] = __builtin_amdgcn_mfma_f32_16x16x32_bf16(al[m], bh[n], acc[m][n], 0, 0, 0);
                }
        }
    }

    // epilogue: C/D layout col = lane&15 (t), row = (lane>>4)*4 + reg (o)
    const unsigned short* thi = tpl;
    const unsigned short* tlo = tpl + SLAB;
    float sn[4] = {0.f, 0.f, 0.f, 0.f};
#pragma unroll
    for (int m = 0; m < 4; ++m) {
        int ob4 = obase + mrow + m * 16 + kq * 4;
        float4v bias = *(const float4v*)&bconv[ob4];
#pragma unroll
        for (int n = 0; n < 4; ++n) {
            int t = ncol + n * 16 + r16;
            size_t sidx = ((size_t)b * kT + t) * kC + ob4;
            ushort4v sh = *(const ushort4v*)&thi[sidx];
            ushort4v sl = *(const ushort4v*)&tlo[sidx];
#pragma unroll
            for (int j = 0; j < 4; ++j) {
                float v = acc[m][n][j] + bias[j];
                v = v >= 0.f ? v : 0.2f * v;
                float hp = v + bf_f(sh[j]) + bf_f(sl[j]);   // + skip (normalized prev h)
                hpre[((size_t)b * kC + ob4 + j) * kT + t] = hp;
                sn[n] += hp * hp;
            }
        }
    }
#pragma unroll
    for (int n = 0; n < 4; ++n)
        red[w * 256 + kq * 64 + n * 16 + r16] = sn[n];
    __syncthreads();
    if (tid < kT) {
        int t = tid;
        int base = (t < 64) ? 0 : 2;
        int tl = t & 63;
        float s = 0.f;
#pragma unroll
        for (int ww = 0; ww < 2; ++ww)
#pragma unroll
            for (int q = 0; q < 4; ++q)
                s += red[(base + ww) * 256 + q * 64 + tl];
        ssp[((size_t)blockIdx.x * kB + b) * kT + t] = s;
    }
}

// ---------------------------------------------------------------------------
// rnorm[b][t] = 1 / (sqrt(sum over 8 o-block partials) + 1e-8) (unchanged)
// ---------------------------------------------------------------------------
__global__ void normfac(const float* __restrict__ ssp, float* __restrict__ rn) {
    int b = blockIdx.x;
    int t = threadIdx.x;
    float s = 0.f;
#pragma unroll
    for (int j = 0; j < kOB; ++j) s += ssp[((size_t)j * kB + b) * kT + t];
    rn[b * kT + t] = 1.0f / (sqrtf(s) + 1e-8f);
}

// ---------------------------------------------------------------------------
// Transpose + (optional) normalize + acc: hsrc [b][c][t] fp32 -> hT planes
// [pl][b][t][c] bf16 hi/lo.  MODE 1: multiply rnorm, update acc (fp32 [c][t]).
// MODE 0: init pass for h0 (no norm, no acc).
// ---------------------------------------------------------------------------
template <int MODE>
__global__ void trans_kernel(const float* __restrict__ hsrc,
                             const float* __restrict__ rn,
                             float* __restrict__ acc,
                             unsigned short* __restrict__ tpl,
                             int first) {
    __shared__ float tile[64][68];
    int b = blockIdx.x;
    int c0 = blockIdx.y * 64;
    int t0 = blockIdx.z * 64;
    int tid = threadIdx.x;
#pragma unroll
    for (int r = 0; r < 4; ++r) {
        int row = r * 16 + (tid >> 4);
        int col = (tid & 15) * 4;
        size_t idx = ((size_t)b * kC + c0 + row) * kT + t0 + col;
        float4 v = *(const float4*)&hsrc[idx];
        if constexpr (MODE) {
            float4 rv = *(const float4*)&rn[b * kT + t0 + col];
            v.x *= rv.x; v.y *= rv.y; v.z *= rv.z; v.w *= rv.w;
            if (first) {
                *(float4*)&acc[idx] = v;
            } else {
                float4 a = *(const float4*)&acc[idx];
                a.x += v.x; a.y += v.y; a.z += v.z; a.w += v.w;
                *(float4*)&acc[idx] = a;
            }
        }
        *(float4*)&tile[row][col] = v;
    }
    __syncthreads();
    unsigned short* thi = tpl;
    unsigned short* tlo = tpl + SLAB;
#pragma unroll
    for (int r = 0; r < 2; ++r) {
        int trow = r * 32 + (tid >> 3);
        int cc = (tid & 7) * 8;
        short8v hp, lp;
#pragma unroll
        for (int j = 0; j < 8; ++j) {
            float f = tile[cc + j][trow];
            unsigned short h = bf_hi(f);
            hp[j] = (short)h;
            lp[j] = (short)bf_hi(f - bf_f(h));
        }
        size_t dst = ((size_t)b * kT + t0 + trow) * kC + c0 + cc;
        *(short8v*)&thi[dst] = hp;
        *(short8v*)&tlo[dst] = lp;
    }
}

// ---------------------------------------------------------------------------
// switch partials (unchanged, acc layout still [b][c][t])
// ---------------------------------------------------------------------------
__global__ void switch_partial(const float* __restrict__ acc,
                               const float* __restrict__ w_sw,
                               float* __restrict__ swp) {
    int b = blockIdx.x;
    int cblk = blockIdx.y;
    int t = threadIdx.x & 127;
    int half = threadIdx.x >> 7;
    int cbase = cblk * 128 + half * 64;
    const float* arow = acc + ((size_t)b * kC + cbase) * kT + t;
    float p = 0.f;
    for (int j = 0; j < 64; ++j) p += w_sw[cbase + j] * arow[(size_t)j * kT];
    __shared__ float red2[2][128];
    red2[half][t] = p;
    __syncthreads();
    if (half == 0)
        swp[((size_t)cblk * kB + b) * kT + t] = red2[0][t] + red2[1][t];
}

// ---------------------------------------------------------------------------
// Top-16 of |switch+b_sw| (unchanged)
// ---------------------------------------------------------------------------
__global__ void topk_kernel(const float* __restrict__ swp,
                            const float* __restrict__ b_sw,
                            float* __restrict__ vals, int* __restrict__ idxs) {
    int b = blockIdx.x;
    int t = threadIdx.x;
    __shared__ float cur[128];
    __shared__ float rv[128];
    __shared__ int ri[128];
    {
        float s = b_sw[0];
#pragma unroll
        for (int j = 0; j < kC / 128; ++j)
            s += swp[((size_t)j * kB + b) * kT + t];
        cur[t] = fabsf(s);
    }
    __syncthreads();
    for (int r = 0; r < kEv; ++r) {
        rv[t] = cur[t];
        ri[t] = t;
        __syncthreads();
        for (int s = 64; s >= 1; s >>= 1) {
            if (t < s) {
                float v2 = rv[t + s];
                int i2 = ri[t + s];
                if (v2 > rv[t] || (v2 == rv[t] && i2 < ri[t])) { rv[t] = v2; ri[t] = i2; }
            }
            __syncthreads();
        }
        if (t == 0) {
            vals[b * kEv + r] = rv[0];
            idxs[b * kEv + r] = ri[0];
            cur[ri[0]] = -1.0f;
        }
        __syncthreads();
    }
}

// ---------------------------------------------------------------------------
// Final (unchanged)
// ---------------------------------------------------------------------------
__global__ void final_kernel(const float* __restrict__ acc,
                             const float* __restrict__ Mt,
                             const float* __restrict__ pbias,
                             const float* __restrict__ b_par,
                             const float* __restrict__ vals,
                             const int* __restrict__ idxs,
                             float* __restrict__ out) {
    int bn = blockIdx.x;
    int b = bn >> 4;
    int tid = threadIdx.x;
    __shared__ float gs[kC];
    __shared__ float redf[4][64];
    int idx = idxs[bn];
    float val = vals[bn];
#pragma unroll
    for (int j = 0; j < 4; ++j) {
        int k = tid * 4 + j;
        gs[k] = acc[((size_t)b * kC + k) * kT + idx];
    }
    __syncthreads();
    int kg = tid >> 6;
    int pp = tid & 63;
    float partial = 0.f;
    if (pp < kPar) {
        for (int j = 0; j < 256; ++j) {
            int k = kg * 256 + j;
            partial += Mt[(size_t)k * kPar + pp] * gs[k];
        }
    }
    redf[kg][pp] = partial;
    __syncthreads();
    if (kg == 0 && pp < kPar) {
        float s = redf[0][pp] + redf[1][pp] + redf[2][pp] + redf[3][pp];
        out[(size_t)bn * kPar + pp] = val * (s + pbias[pp]) + b_par[pp];
    }
}

// ---------------------------------------------------------------------------
extern "C" void kernel_launch(void* const* d_in, const int* in_sizes, int n_in,
                              void* d_out, int out_size, void* d_ws, size_t ws_size,
                              hipStream_t stream) {
    (void)in_sizes; (void)n_in; (void)out_size; (void)ws_size;
    const float* x      = (const float*)d_in[0];
    const float* w_spec = (const float*)d_in[1];
    const float* b_spec = (const float*)d_in[2];
    const float* w_pos  = (const float*)d_in[3];
    const float* b_pos  = (const float*)d_in[4];
    const float* enc_w  = (const float*)d_in[5];
    const float* enc_b  = (const float*)d_in[6];
    const float* w_vec  = (const float*)d_in[7];
    const float* b_vec  = (const float*)d_in[8];
    const float* w_sw   = (const float*)d_in[9];
    const float* b_sw   = (const float*)d_in[10];
    const float* w_par  = (const float*)d_in[11];
    const float* b_par  = (const float*)d_in[12];
    float* out = (float*)d_out;

    float* hpre = (float*)d_ws;                         // SLAB f32 (also h0)
    float* acc  = hpre + SLAB;                          // SLAB f32
    unsigned short* tpl = (unsigned short*)(acc + SLAB);  // 2*SLAB bf16 (hi, lo)
    unsigned short* wpl = tpl + 2 * SLAB;               // 4*kC*kC bf16
    float* posproj = (float*)(wpl + (size_t)4 * kC * kC);
    float* ssp   = posproj + (size_t)kC * kT;           // 8*B*T
    float* rnorm = ssp + (size_t)kOB * kB * kT;         // B*T
    float* swp   = rnorm + (size_t)kB * kT;             // 8*B*T
    float* vals  = swp + (size_t)kOB * kB * kT;         // B*16
    int*   idxs  = (int*)(vals + kB * kEv);             // B*16
    float* Mt    = (float*)(idxs + kB * kEv);           // 1024*57
    float* pbias = Mt + (size_t)kC * kPar;              // 57

    pos_kernel<<<kC, kT, 0, stream>>>(w_pos, b_pos, posproj);
    mt_kernel<<<kPar + 1, 256, 0, stream>>>(w_par, w_vec, b_vec, Mt, pbias);
    spec_gemm<<<dim3(kC / BM, kB), NTHR, 0, stream>>>(x, w_spec, b_spec, posproj, hpre);
    // h0 -> bf16 hi/lo planes (no norm, no acc)
    trans_kernel<0><<<dim3(kB, kC / 64, kT / 64), NTHR, 0, stream>>>(
        hpre, rnorm, acc, tpl, 0);

    const int dils[kLayers] = {1, 2, 4, 8, 16, 32, 64, 1};
    for (int i = 0; i < kLayers; ++i) {
        const float* wi = enc_w + (size_t)i * kC * kC * 2;
        const float* bi = enc_b + (size_t)i * kC;
        wconv_kernel<<<kC, NTHR, 0, stream>>>(wi, wpl);
        dim3 grid(kC / BM, kB);
        switch (dils[i]) {
            case 1:  conv_mfma<1><<<grid, NTHR, 0, stream>>>(tpl, wpl, bi, hpre, ssp); break;
            case 2:  conv_mfma<2><<<grid, NTHR, 0, stream>>>(tpl, wpl, bi, hpre, ssp); break;
            case 4:  conv_mfma<4><<<grid, NTHR, 0, stream>>>(tpl, wpl, bi, hpre, ssp); break;
            case 8:  conv_mfma<8><<<grid, NTHR, 0, stream>>>(tpl, wpl, bi, hpre, ssp); break;
            case 16: conv_mfma<16><<<grid, NTHR, 0, stream>>>(tpl, wpl, bi, hpre, ssp); break;
            case 32: conv_mfma<32><<<grid, NTHR, 0, stream>>>(tpl, wpl, bi, hpre, ssp); break;
            case 64: conv_mfma<64><<<grid, NTHR, 0, stream>>>(tpl, wpl, bi, hpre, ssp); break;
        }
        normfac<<<kB, kT, 0, stream>>>(ssp, rnorm);
        trans_kernel<1><<<dim3(kB, kC / 64, kT / 64), NTHR, 0, stream>>>(
            hpre, rnorm, acc, tpl, i == 0 ? 1 : 0);
    }

    switch_partial<<<dim3(kB, kC / 128), 256, 0, stream>>>(acc, w_sw, swp);
    topk_kernel<<<kB, 128, 0, stream>>>(swp, b_sw, vals, idxs);
    final_kernel<<<kB * kEv, 256, 0, stream>>>(acc, Mt, pbias, b_par, vals, idxs, out);
}